// Round 4
// baseline (163.812 us; speedup 1.0000x reference)
//
#include <hip/hip_runtime.h>
#include <hip/hip_bf16.h>
#include <hip/hip_fp16.h>
#include <math.h>

// Attention_1322849927553: B=8, S=1024, D=512, H=8, hd=64, additive pos bias.
// Round 4 == Round 3 resubmit (round 3 hit GPUAcquisitionTimeout, never ran):
// 16 waves/CU (grid 1024, 40KB LDS, XOR-swizzled P), fp16 bias table
// (prep pass, log2e folded, per-lane-contiguous layout), bias prefetch 1 tile
// ahead, XCD-chunked block swizzle. ws tiers: fp16-bias -> fp32-bias -> round-1.

typedef __attribute__((ext_vector_type(8))) short short8;
typedef __attribute__((ext_vector_type(4))) float f32x4;
typedef __attribute__((ext_vector_type(4))) unsigned short u16x4;
typedef __attribute__((ext_vector_type(8))) unsigned short u16x8;

#define SEQ   1024
#define DM    512
#define HD    64
#define NH    8
#define LOG2E 1.4426950408889634f
#define QSCALE (0.125f * LOG2E)

__device__ __forceinline__ unsigned short f2bf(float f) {
    unsigned u = __float_as_uint(f);
    u += 0x7fffu + ((u >> 16) & 1u);   // RNE
    return (unsigned short)(u >> 16);
}
__device__ __forceinline__ u16x4 pack4(float a, float b, float c, float d) {
    u16x4 r; r[0] = f2bf(a); r[1] = f2bf(b); r[2] = f2bf(c); r[3] = f2bf(d);
    return r;
}
__device__ __forceinline__ short8 pack8(const float* x) {
    short8 r;
#pragma unroll
    for (int i = 0; i < 8; ++i) r[i] = (short)f2bf(x[i]);
    return r;
}
__device__ __forceinline__ float fexp2(float x) {
#if __has_builtin(__builtin_amdgcn_exp2f)
    return __builtin_amdgcn_exp2f(x);
#else
    return exp2f(x);
#endif
}
__device__ __forceinline__ void gll16(const void* g, void* l) {
    __builtin_amdgcn_global_load_lds(
        (const __attribute__((address_space(1))) unsigned*)g,
        (__attribute__((address_space(3))) unsigned*)l, 16, 0, 0);
}
__device__ __forceinline__ float h2f(unsigned short u) {
    __half hh = *reinterpret_cast<__half*>(&u);
    return __half2float(hh);
}
__device__ __forceinline__ unsigned short f2h(float v) {
    __half hh = __float2half(v);
    return *reinterpret_cast<unsigned short*>(&hh);
}

// ---- prep: K -> bf16, tile-major [bh][st][64s][64d], chunk^=(s&7) ----
__global__ __launch_bounds__(256)
void prep_k(const float* __restrict__ k, short* __restrict__ kws) {
    int tid = blockIdx.x * 256 + threadIdx.x;      // 524288
    int d8 = tid & 7, h = (tid >> 3) & 7, s = (tid >> 6) & 1023, b = tid >> 16;
    const float* src = k + ((size_t)(b * SEQ + s) * DM + h * HD + d8 * 8);
    float4 x0 = *(const float4*)src, x1 = *(const float4*)(src + 4);
    float xs[8] = {x0.x, x0.y, x0.z, x0.w, x1.x, x1.y, x1.z, x1.w};
    int bh = b * NH + h;
    size_t idx = (size_t)(bh * 16 + (s >> 6)) * 4096 + (s & 63) * 64 + ((d8 ^ (s & 7)) * 8);
    *(short8*)(kws + idx) = pack8(xs);
}

// ---- prep: V -> bf16 transposed, tile-major [bh][st][64d][64s], chunk^=(d&7) ----
__global__ __launch_bounds__(256)
void prep_v(const float* __restrict__ v, short* __restrict__ vtws) {
    __shared__ short Vs[64][72];
    int bid = blockIdx.x;                // 1024
    int st = bid & 15, h = (bid >> 4) & 7, b = bid >> 7;
    int t = threadIdx.x;
    {
        int sl = t >> 2, dc = t & 3;
        const float* src = v + ((size_t)(b * SEQ + st * 64 + sl) * DM + h * HD + dc * 16);
        float4 a0 = ((const float4*)src)[0], a1 = ((const float4*)src)[1],
               a2 = ((const float4*)src)[2], a3 = ((const float4*)src)[3];
        float xs0[8] = {a0.x, a0.y, a0.z, a0.w, a1.x, a1.y, a1.z, a1.w};
        float xs1[8] = {a2.x, a2.y, a2.z, a2.w, a3.x, a3.y, a3.z, a3.w};
        *(short8*)&Vs[sl][dc * 16]     = pack8(xs0);
        *(short8*)&Vs[sl][dc * 16 + 8] = pack8(xs1);
    }
    __syncthreads();
    {
        int d = t >> 2, sc = t & 3;
        short vals[16];
#pragma unroll
        for (int j = 0; j < 16; ++j) vals[j] = Vs[sc * 16 + j][d];
        short8 w0, w1;
#pragma unroll
        for (int j = 0; j < 8; ++j) { w0[j] = vals[j]; w1[j] = vals[8 + j]; }
        int bh = b * NH + h;
        size_t base = (size_t)(bh * 16 + st) * 4096 + d * 64;
        int c0 = (sc * 2) ^ (d & 7), c1 = (sc * 2 + 1) ^ (d & 7);
        *(short8*)(vtws + base + c0 * 8) = w0;
        *(short8*)(vtws + base + c1 * 8) = w1;
    }
}

// ---- prep: bias fp32 -> fp16 * LOG2E, layout [h][kt][qrow][g][mt][r] ----
__global__ __launch_bounds__(256)
void prep_bias(const float* __restrict__ bias, unsigned short* __restrict__ b16) {
    int tid = blockIdx.x * 256 + threadIdx.x;      // 2,097,152
    int h = tid >> 18;
    int rem = tid & 262143;
    int i = rem >> 8;
    int j = (rem & 255) * 4;
    float4 x = *(const float4*)(bias + ((size_t)(h * 1024 + i) * 1024 + j));
    int kt = j >> 6, jl = j & 63, mt = jl >> 4, gg = (jl >> 2) & 3;
    u16x4 r;
    r[0] = f2h(x.x * LOG2E); r[1] = f2h(x.y * LOG2E);
    r[2] = f2h(x.z * LOG2E); r[3] = f2h(x.w * LOG2E);
    *(u16x4*)(b16 + ((size_t)((h * 16 + kt) * 1024 + i) * 64 + gg * 16 + mt * 4)) = r;
}

// ---- fused attention v3: 64 q-rows/block, 16/wave, 4 blocks/CU ----
// BM=0: fp16 bias table; BM=1: fp32 bias in original layout.
template<int BM>
__global__ __launch_bounds__(256, 4)
void attn_fwd3(const float* __restrict__ q,
               const float* __restrict__ bias32,
               const unsigned short* __restrict__ bias16,
               const short* __restrict__ kws,
               const short* __restrict__ vtws,
               float* __restrict__ out)
{
    __shared__ short Ksh[2][4096];     // [64 s][64 d], chunk^=(s&7)
    __shared__ short Vsh[2][4096];     // [64 d][64 s], chunk^=(d&7)
    __shared__ short Plds[4][16][64];  // per-wave P, 8B-chunk ^= 2*(qr&7)

    const int t = threadIdx.x;
    const int wid = t >> 6, lane = t & 63;
    const int qr = lane & 15, g = lane >> 4;

    // XCD-chunked swizzle: XCD x (= bid%8) gets logical blocks [x*128, x*128+128)
    int raw = blockIdx.x;
    int lid = (raw & 7) * 128 + (raw >> 3);
    const int b = lid & 7;
    const int h = (lid >> 3) & 7;
    const int qt = lid >> 6;           // 0..15
    const int qbase = qt * 64 + wid * 16;
    const int bh = b * NH + h;

    // ---- Q fragments (B operand), scale*log2e folded ----
    const float* qp = q + ((size_t)(b * SEQ + qbase + qr) * DM + h * HD);
    short8 qf[2];
#pragma unroll
    for (int c = 0; c < 2; ++c) {
        float4 x0 = *(const float4*)(qp + g * 8 + 32 * c);
        float4 x1 = *(const float4*)(qp + g * 8 + 32 * c + 4);
        float xs[8] = {x0.x * QSCALE, x0.y * QSCALE, x0.z * QSCALE, x0.w * QSCALE,
                       x1.x * QSCALE, x1.y * QSCALE, x1.z * QSCALE, x1.w * QSCALE};
        qf[c] = pack8(xs);
    }

    f32x4 o[4];
#pragma unroll
    for (int nt = 0; nt < 4; ++nt) o[nt] = (f32x4){0.f, 0.f, 0.f, 0.f};
    float mrun = -INFINITY, lrun = 0.f;

    const size_t tb0 = (size_t)bh * 16 * 4096;

    u16x8 bn0, bn1;      // BM==0 prefetch regs
    float4 bnf[4];       // BM==1 prefetch regs

    // ---- prologue: stage tile 0, prefetch bias tile 0 ----
    {
        const short* gk = kws + tb0 + wid * 512 + lane * 8;
        const short* gv = vtws + tb0 + wid * 512 + lane * 8;
        gll16(gk,        &Ksh[0][wid * 512]);
        gll16(gk + 2048, &Ksh[0][2048 + wid * 512]);
        gll16(gv,        &Vsh[0][wid * 512]);
        gll16(gv + 2048, &Vsh[0][2048 + wid * 512]);
        if constexpr (BM == 0) {
            const unsigned short* bp =
                bias16 + ((size_t)((h * 16 + 0) * 1024 + qbase + qr) * 64 + g * 16);
            bn0 = *(const u16x8*)bp;
            bn1 = *(const u16x8*)(bp + 8);
        } else {
            const float* bp = bias32 + ((size_t)(h * SEQ + qbase + qr) * SEQ + g * 4);
#pragma unroll
            for (int mt = 0; mt < 4; ++mt) bnf[mt] = *(const float4*)(bp + 16 * mt);
        }
    }
    __syncthreads();

    int cur = 0;
    for (int kt = 0; kt < 16; ++kt) {
        // ---- snapshot this tile's bias from prefetch regs ----
        float bf[4][4];
        if constexpr (BM == 0) {
#pragma unroll
            for (int r = 0; r < 4; ++r) {
                bf[0][r] = h2f(bn0[r]);
                bf[1][r] = h2f(bn0[4 + r]);
                bf[2][r] = h2f(bn1[r]);
                bf[3][r] = h2f(bn1[4 + r]);
            }
        } else {
#pragma unroll
            for (int mt = 0; mt < 4; ++mt)
#pragma unroll
                for (int r = 0; r < 4; ++r) bf[mt][r] = ((const float*)&bnf[mt])[r];
        }

        // ---- stage next K/V tile ----
        if (kt < 15) {
            const size_t tb = tb0 + (size_t)(kt + 1) * 4096;
            const short* gk = kws + tb + wid * 512 + lane * 8;
            const short* gv = vtws + tb + wid * 512 + lane * 8;
            int nxt = cur ^ 1;
            gll16(gk,        &Ksh[nxt][wid * 512]);
            gll16(gk + 2048, &Ksh[nxt][2048 + wid * 512]);
            gll16(gv,        &Vsh[nxt][wid * 512]);
            gll16(gv + 2048, &Vsh[nxt][2048 + wid * 512]);
        }
        // ---- prefetch next tile's bias ----
        {
            int ktn = kt < 15 ? kt + 1 : 15;
            if constexpr (BM == 0) {
                const unsigned short* bp =
                    bias16 + ((size_t)((h * 16 + ktn) * 1024 + qbase + qr) * 64 + g * 16);
                bn0 = *(const u16x8*)bp;
                bn1 = *(const u16x8*)(bp + 8);
            } else {
                const float* bp =
                    bias32 + ((size_t)(h * SEQ + qbase + qr) * SEQ + ktn * 64 + g * 4);
#pragma unroll
                for (int mt = 0; mt < 4; ++mt) bnf[mt] = *(const float4*)(bp + 16 * mt);
            }
        }

        // ---- QK^T: S^T = mfma(K, Q); lane holds S[q=qr][k=16mt+4g+r] ----
        f32x4 acc[4];
#pragma unroll
        for (int mt = 0; mt < 4; ++mt) acc[mt] = (f32x4){0.f, 0.f, 0.f, 0.f};
        __builtin_amdgcn_s_setprio(1);
#pragma unroll
        for (int mt = 0; mt < 4; ++mt) {
#pragma unroll
            for (int c = 0; c < 2; ++c) {
                const short8 kf = *(const short8*)
                    &Ksh[cur][(qr + 16 * mt) * 64 + ((g + 4 * c) ^ (qr & 7)) * 8];
                acc[mt] = __builtin_amdgcn_mfma_f32_16x16x32_bf16(kf, qf[c], acc[mt], 0, 0, 0);
            }
        }
        __builtin_amdgcn_s_setprio(0);

        // ---- online softmax (exp2 domain; bias pre-scaled for BM=0) ----
        float s[4][4];
        float tmax = -INFINITY;
#pragma unroll
        for (int mt = 0; mt < 4; ++mt)
#pragma unroll
            for (int r = 0; r < 4; ++r) {
                float val;
                if constexpr (BM == 0) val = acc[mt][r] + bf[mt][r];
                else                   val = fmaf(bf[mt][r], LOG2E, acc[mt][r]);
                s[mt][r] = val;
                tmax = fmaxf(tmax, val);
            }
        tmax = fmaxf(tmax, __shfl_xor(tmax, 16));
        tmax = fmaxf(tmax, __shfl_xor(tmax, 32));
        const float mnew = fmaxf(mrun, tmax);
        float ssum = 0.f;
#pragma unroll
        for (int mt = 0; mt < 4; ++mt) {
            float e0 = fexp2(s[mt][0] - mnew);
            float e1 = fexp2(s[mt][1] - mnew);
            float e2 = fexp2(s[mt][2] - mnew);
            float e3 = fexp2(s[mt][3] - mnew);
            ssum += (e0 + e1) + (e2 + e3);
            *(u16x4*)&Plds[wid][qr][((4 * mt + g) ^ (2 * (qr & 7))) * 4] =
                pack4(e0, e1, e2, e3);
        }
        ssum += __shfl_xor(ssum, 16);
        ssum += __shfl_xor(ssum, 32);
        const float scs = fexp2(mrun - mnew);   // first iter: exp2(-inf)=0
        lrun = lrun * scs + ssum;
        mrun = mnew;

        // ---- rescale O (rows q = 4g+r in PV layout) ----
        float scr[4];
#pragma unroll
        for (int r = 0; r < 4; ++r) scr[r] = __shfl(scs, g * 4 + r);
#pragma unroll
        for (int nt = 0; nt < 4; ++nt)
#pragma unroll
            for (int r = 0; r < 4; ++r) o[nt][r] *= scr[r];

        // P writes (cross-lane within wave) must land before PV reads
        asm volatile("s_waitcnt lgkmcnt(0)" ::: "memory");
        __builtin_amdgcn_sched_barrier(0);

        // ---- PV: O += mfma(P, V^T-frag) ----
        __builtin_amdgcn_s_setprio(1);
#pragma unroll
        for (int c = 0; c < 2; ++c) {
            const int ch0 = (2 * g + 8 * c) ^ (2 * (qr & 7));
            short8 pf = *(const short8*)&Plds[wid][qr][ch0 * 4];
#pragma unroll
            for (int nt = 0; nt < 4; ++nt) {
                short8 vf = *(const short8*)
                    &Vsh[cur][(qr + 16 * nt) * 64 + ((g + 4 * c) ^ (qr & 7)) * 8];
                o[nt] = __builtin_amdgcn_mfma_f32_16x16x32_bf16(pf, vf, o[nt], 0, 0, 0);
            }
        }
        __builtin_amdgcn_s_setprio(0);

        __syncthreads();   // next tile staged + buffers protected
        cur ^= 1;
    }

    // ---- epilogue ----
    const float inv = 1.0f / lrun;
    float invr[4];
#pragma unroll
    for (int r = 0; r < 4; ++r) invr[r] = __shfl(inv, g * 4 + r);
    float* op = out + ((size_t)(b * SEQ + qbase) * DM + h * HD + qr);
#pragma unroll
    for (int nt = 0; nt < 4; ++nt)
#pragma unroll
        for (int r = 0; r < 4; ++r)
            op[(size_t)(g * 4 + r) * DM + nt * 16] = o[nt][r] * invr[r];
}

// ---------------- round-1 kernel kept as last-resort fallback ----------------
__global__ __launch_bounds__(256, 3)
void attn_fwd(const float* __restrict__ q, const float* __restrict__ k,
              const float* __restrict__ v, const float* __restrict__ bias,
              float* __restrict__ out)
{
    __shared__ short Klds[64][72];
    __shared__ short Vt[64][72];
    __shared__ short Pl[4][16][72];

    const int t = threadIdx.x;
    const int wid = t >> 6;
    const int lane = t & 63;
    const int qr = lane & 15;
    const int g = lane >> 4;

    int idx = blockIdx.x;
    const int b = idx & 7;  idx >>= 3;
    const int h = idx & 7;
    const int qtile = idx >> 3;
    const int qbase = qtile * 64 + wid * 16;

    const float* qp = q + ((b * SEQ + qbase + qr) * DM + h * HD);
    short8 qf[2];
#pragma unroll
    for (int c = 0; c < 2; ++c) {
        float4 x0 = *reinterpret_cast<const float4*>(qp + g * 8 + 32 * c);
        float4 x1 = *reinterpret_cast<const float4*>(qp + g * 8 + 32 * c + 4);
        float xs[8] = {x0.x * 0.125f, x0.y * 0.125f, x0.z * 0.125f, x0.w * 0.125f,
                       x1.x * 0.125f, x1.y * 0.125f, x1.z * 0.125f, x1.w * 0.125f};
        qf[c] = pack8(xs);
    }

    f32x4 o[4];
#pragma unroll
    for (int nt = 0; nt < 4; ++nt) o[nt] = (f32x4){0.f, 0.f, 0.f, 0.f};
    float mrun = -INFINITY, lrun = 0.f;

    const int jrow = t & 63;
    const int cc = t >> 6;

    for (int kt = 0; kt < 16; ++kt) {
        const int kbase = kt * 64;
        {
            const float4* kp4 = reinterpret_cast<const float4*>(
                k + ((b * SEQ + kbase + jrow) * DM + h * HD + cc * 16));
            float4 a0 = kp4[0], a1 = kp4[1], a2 = kp4[2], a3 = kp4[3];
            u16x4* dst = reinterpret_cast<u16x4*>(&Klds[jrow][cc * 16]);
            dst[0] = pack4(a0.x, a0.y, a0.z, a0.w);
            dst[1] = pack4(a1.x, a1.y, a1.z, a1.w);
            dst[2] = pack4(a2.x, a2.y, a2.z, a2.w);
            dst[3] = pack4(a3.x, a3.y, a3.z, a3.w);
        }
        {
            const float* vp = v + ((b * SEQ + kbase + cc * 16) * DM + h * HD + jrow);
            float vv[16];
#pragma unroll
            for (int jj = 0; jj < 16; ++jj) vv[jj] = vp[jj * DM];
            u16x4* dst = reinterpret_cast<u16x4*>(&Vt[jrow][cc * 16]);
            dst[0] = pack4(vv[0], vv[1], vv[2], vv[3]);
            dst[1] = pack4(vv[4], vv[5], vv[6], vv[7]);
            dst[2] = pack4(vv[8], vv[9], vv[10], vv[11]);
            dst[3] = pack4(vv[12], vv[13], vv[14], vv[15]);
        }
        __syncthreads();

        const float* bp = bias + ((h * SEQ + qbase + qr) * SEQ + kbase + g * 4);
        float4 bv0 = *reinterpret_cast<const float4*>(bp);
        float4 bv1 = *reinterpret_cast<const float4*>(bp + 16);
        float4 bv2 = *reinterpret_cast<const float4*>(bp + 32);
        float4 bv3 = *reinterpret_cast<const float4*>(bp + 48);

        f32x4 acc[4];
#pragma unroll
        for (int mt = 0; mt < 4; ++mt) {
            f32x4 a = (f32x4){0.f, 0.f, 0.f, 0.f};
#pragma unroll
            for (int c = 0; c < 2; ++c) {
                short8 kf = *reinterpret_cast<const short8*>(
                    &Klds[qr + 16 * mt][g * 8 + 32 * c]);
                a = __builtin_amdgcn_mfma_f32_16x16x32_bf16(kf, qf[c], a, 0, 0, 0);
            }
            acc[mt] = a;
        }
        acc[0][0] += bv0.x; acc[0][1] += bv0.y; acc[0][2] += bv0.z; acc[0][3] += bv0.w;
        acc[1][0] += bv1.x; acc[1][1] += bv1.y; acc[1][2] += bv1.z; acc[1][3] += bv1.w;
        acc[2][0] += bv2.x; acc[2][1] += bv2.y; acc[2][2] += bv2.z; acc[2][3] += bv2.w;
        acc[3][0] += bv3.x; acc[3][1] += bv3.y; acc[3][2] += bv3.z; acc[3][3] += bv3.w;

        float tmax = acc[0][0];
#pragma unroll
        for (int mt = 0; mt < 4; ++mt)
#pragma unroll
            for (int r = 0; r < 4; ++r) tmax = fmaxf(tmax, acc[mt][r]);
        tmax = fmaxf(tmax, __shfl_xor(tmax, 16));
        tmax = fmaxf(tmax, __shfl_xor(tmax, 32));
        const float mnew = fmaxf(mrun, tmax);

        float p[4][4];
        float ssum = 0.f;
#pragma unroll
        for (int mt = 0; mt < 4; ++mt)
#pragma unroll
            for (int r = 0; r < 4; ++r) {
                float e = __expf(acc[mt][r] - mnew);
                p[mt][r] = e;
                ssum += e;
            }
        ssum += __shfl_xor(ssum, 16);
        ssum += __shfl_xor(ssum, 32);
        const float scv = __expf(mrun - mnew);
        lrun = lrun * scv + ssum;
        mrun = mnew;

#pragma unroll
        for (int mt = 0; mt < 4; ++mt) {
            *reinterpret_cast<u16x4*>(&Pl[wid][qr][16 * mt + g * 4]) =
                pack4(p[mt][0], p[mt][1], p[mt][2], p[mt][3]);
        }

        float scr[4];
#pragma unroll
        for (int r = 0; r < 4; ++r) scr[r] = __shfl(scv, g * 4 + r);
#pragma unroll
        for (int nt = 0; nt < 4; ++nt)
#pragma unroll
            for (int r = 0; r < 4; ++r) o[nt][r] *= scr[r];

        asm volatile("s_waitcnt lgkmcnt(0)" ::: "memory");
        __builtin_amdgcn_sched_barrier(0);

        short8 pf0 = *reinterpret_cast<const short8*>(&Pl[wid][qr][g * 8]);
        short8 pf1 = *reinterpret_cast<const short8*>(&Pl[wid][qr][g * 8 + 32]);
#pragma unroll
        for (int nt = 0; nt < 4; ++nt) {
            short8 vf0 = *reinterpret_cast<const short8*>(&Vt[qr + 16 * nt][g * 8]);
            short8 vf1 = *reinterpret_cast<const short8*>(&Vt[qr + 16 * nt][g * 8 + 32]);
            o[nt] = __builtin_amdgcn_mfma_f32_16x16x32_bf16(pf0, vf0, o[nt], 0, 0, 0);
            o[nt] = __builtin_amdgcn_mfma_f32_16x16x32_bf16(pf1, vf1, o[nt], 0, 0, 0);
        }
        __syncthreads();
    }

    const float inv = 1.0f / lrun;
    float invr[4];
#pragma unroll
    for (int r = 0; r < 4; ++r) invr[r] = __shfl(inv, g * 4 + r);

    float* op = out + ((b * SEQ + qbase) * DM + h * HD + qr);
#pragma unroll
    for (int nt = 0; nt < 4; ++nt)
#pragma unroll
        for (int r = 0; r < 4; ++r)
            op[(g * 4 + r) * DM + nt * 16] = o[nt][r] * invr[r];
}

extern "C" void kernel_launch(void* const* d_in, const int* in_sizes, int n_in,
                              void* d_out, int out_size, void* d_ws, size_t ws_size,
                              hipStream_t stream) {
    const float* q    = (const float*)d_in[0];
    const float* k    = (const float*)d_in[1];
    const float* v    = (const float*)d_in[2];
    const float* bias = (const float*)d_in[3];
    float* out        = (float*)d_out;

    const size_t kv_elems  = (size_t)8 * NH * SEQ * HD;        // 4,194,304 shorts each
    const size_t kv_bytes  = 2 * kv_elems * sizeof(short);     // 16,777,216
    const size_t b16_bytes = (size_t)NH * SEQ * SEQ * 2;       // 16,777,216

    if (ws_size >= b16_bytes + kv_bytes) {
        unsigned short* b16 = (unsigned short*)d_ws;
        short* kws  = (short*)((char*)d_ws + b16_bytes);
        short* vtws = kws + kv_elems;
        prep_bias<<<dim3(8192), dim3(256), 0, stream>>>(bias, b16);
        prep_k<<<dim3(2048), dim3(256), 0, stream>>>(k, kws);
        prep_v<<<dim3(1024), dim3(256), 0, stream>>>(v, vtws);
        attn_fwd3<0><<<dim3(1024), dim3(256), 0, stream>>>(q, nullptr, b16, kws, vtws, out);
    } else if (ws_size >= kv_bytes) {
        short* kws  = (short*)d_ws;
        short* vtws = kws + kv_elems;
        prep_k<<<dim3(2048), dim3(256), 0, stream>>>(k, kws);
        prep_v<<<dim3(1024), dim3(256), 0, stream>>>(v, vtws);
        attn_fwd3<1><<<dim3(1024), dim3(256), 0, stream>>>(q, bias, nullptr, kws, vtws, out);
    } else {
        attn_fwd<<<dim3(1024), dim3(256), 0, stream>>>(q, k, v, bias, out);
    }
}

// Round 7
// 160.205 us; speedup vs baseline: 1.0225x; 1.0225x over previous
//
#include <hip/hip_runtime.h>
#include <hip/hip_bf16.h>
#include <hip/hip_fp16.h>
#include <math.h>

// Attention_1322849927553: B=8, S=1024, D=512, H=8, hd=64, additive pos bias.
// Round 7 (first HW run of the round-5 design):
// (1) P-LDS removed -> in-register bpermute transform (LDS 32KB, 5 blocks/CU),
// (2) three prep kernels fused into one launch (nullptr-guarded bias branch),
// (3) defer-max rescale (THR=8, exp2 domain).
// ws tiers: fp16-bias -> fp32-bias -> round-1 fallback.

typedef __attribute__((ext_vector_type(8))) short short8;
typedef __attribute__((ext_vector_type(4))) float f32x4;
typedef __attribute__((ext_vector_type(4))) unsigned short u16x4;
typedef __attribute__((ext_vector_type(8))) unsigned short u16x8;

#define SEQ   1024
#define DM    512
#define HD    64
#define NH    8
#define LOG2E 1.4426950408889634f
#define QSCALE (0.125f * LOG2E)
#define RESCALE_THR 8.0f

__device__ __forceinline__ unsigned short f2bf(float f) {
    unsigned u = __float_as_uint(f);
    u += 0x7fffu + ((u >> 16) & 1u);   // RNE
    return (unsigned short)(u >> 16);
}
__device__ __forceinline__ u16x4 pack4(float a, float b, float c, float d) {
    u16x4 r; r[0] = f2bf(a); r[1] = f2bf(b); r[2] = f2bf(c); r[3] = f2bf(d);
    return r;
}
__device__ __forceinline__ short8 pack8(const float* x) {
    short8 r;
#pragma unroll
    for (int i = 0; i < 8; ++i) r[i] = (short)f2bf(x[i]);
    return r;
}
__device__ __forceinline__ float fexp2(float x) {
#if __has_builtin(__builtin_amdgcn_exp2f)
    return __builtin_amdgcn_exp2f(x);
#else
    return exp2f(x);
#endif
}
__device__ __forceinline__ void gll16(const void* g, void* l) {
    __builtin_amdgcn_global_load_lds(
        (const __attribute__((address_space(1))) unsigned*)g,
        (__attribute__((address_space(3))) unsigned*)l, 16, 0, 0);
}
__device__ __forceinline__ float h2f(unsigned short u) {
    __half hh = *reinterpret_cast<__half*>(&u);
    return __half2float(hh);
}
__device__ __forceinline__ unsigned short f2h(float v) {
    __half hh = __float2half(v);
    return *reinterpret_cast<unsigned short*>(&hh);
}

// ---------------- fused prep: bias->fp16 table | K->bf16 swz | V^T->bf16 swz ----
// grid = 8192 (bias) + 2048 (K) + 1024 (V) = 11264 blocks of 256.
__global__ __launch_bounds__(256)
void prep_all(const float* __restrict__ k, const float* __restrict__ v,
              const float* __restrict__ bias,
              short* __restrict__ kws, short* __restrict__ vtws,
              unsigned short* __restrict__ b16)
{
    const int bid = blockIdx.x;
    const int t = threadIdx.x;
    if (bid < 8192) {
        if (b16 == nullptr) return;            // fp32-bias tier: no table
        // bias fp32 -> fp16 * LOG2E, layout [h][kt][qrow][g][mt][r]
        int tid = bid * 256 + t;               // 2,097,152 threads
        int h = tid >> 18;
        int rem = tid & 262143;
        int i = rem >> 8;
        int j = (rem & 255) * 4;
        float4 x = *(const float4*)(bias + ((size_t)(h * 1024 + i) * 1024 + j));
        int kt = j >> 6, jl = j & 63, mt = jl >> 4, gg = (jl >> 2) & 3;
        u16x4 r;
        r[0] = f2h(x.x * LOG2E); r[1] = f2h(x.y * LOG2E);
        r[2] = f2h(x.z * LOG2E); r[3] = f2h(x.w * LOG2E);
        *(u16x4*)(b16 + ((size_t)((h * 16 + kt) * 1024 + i) * 64 + gg * 16 + mt * 4)) = r;
    } else if (bid < 8192 + 2048) {
        // K -> bf16, tile-major [bh][st][64s][64d], chunk^=(s&7)
        int tid = (bid - 8192) * 256 + t;      // 524288
        int d8 = tid & 7, h = (tid >> 3) & 7, s = (tid >> 6) & 1023, b = tid >> 16;
        const float* src = k + ((size_t)(b * SEQ + s) * DM + h * HD + d8 * 8);
        float4 x0 = *(const float4*)src, x1 = *(const float4*)(src + 4);
        float xs[8] = {x0.x, x0.y, x0.z, x0.w, x1.x, x1.y, x1.z, x1.w};
        int bh = b * NH + h;
        size_t idx = (size_t)(bh * 16 + (s >> 6)) * 4096 + (s & 63) * 64 + ((d8 ^ (s & 7)) * 8);
        *(short8*)(kws + idx) = pack8(xs);
    } else {
        // V -> bf16 transposed, tile-major [bh][st][64d][64s], chunk^=(d&7)
        __shared__ short Vs[64][72];
        int bid3 = bid - 10240;                // 0..1023
        int st = bid3 & 15, h = (bid3 >> 4) & 7, b = bid3 >> 7;
        {
            int sl = t >> 2, dc = t & 3;
            const float* src = v + ((size_t)(b * SEQ + st * 64 + sl) * DM + h * HD + dc * 16);
            float4 a0 = ((const float4*)src)[0], a1 = ((const float4*)src)[1],
                   a2 = ((const float4*)src)[2], a3 = ((const float4*)src)[3];
            float xs0[8] = {a0.x, a0.y, a0.z, a0.w, a1.x, a1.y, a1.z, a1.w};
            float xs1[8] = {a2.x, a2.y, a2.z, a2.w, a3.x, a3.y, a3.z, a3.w};
            *(short8*)&Vs[sl][dc * 16]     = pack8(xs0);
            *(short8*)&Vs[sl][dc * 16 + 8] = pack8(xs1);
        }
        __syncthreads();
        {
            int d = t >> 2, sc = t & 3;
            short vals[16];
#pragma unroll
            for (int j = 0; j < 16; ++j) vals[j] = Vs[sc * 16 + j][d];
            short8 w0, w1;
#pragma unroll
            for (int j = 0; j < 8; ++j) { w0[j] = vals[j]; w1[j] = vals[8 + j]; }
            int bh = b * NH + h;
            size_t base = (size_t)(bh * 16 + st) * 4096 + d * 64;
            int c0 = (sc * 2) ^ (d & 7), c1 = (sc * 2 + 1) ^ (d & 7);
            *(short8*)(vtws + base + c0 * 8) = w0;
            *(short8*)(vtws + base + c1 * 8) = w1;
        }
    }
}

// ---- fused attention: 64 q-rows/block, 32KB LDS, reg-P via bpermute ----
// BM=0: fp16 bias table; BM=1: fp32 bias in original layout.
template<int BM>
__global__ __launch_bounds__(256, 5)
void attn_fwd3(const float* __restrict__ q,
               const float* __restrict__ bias32,
               const unsigned short* __restrict__ bias16,
               const short* __restrict__ kws,
               const short* __restrict__ vtws,
               float* __restrict__ out)
{
    __shared__ short Ksh[2][4096];     // [64 s][64 d], chunk^=(s&7)
    __shared__ short Vsh[2][4096];     // [64 d][64 s], chunk^=(d&7)

    const int t = threadIdx.x;
    const int wid = t >> 6, lane = t & 63;
    const int qr = lane & 15, g = lane >> 4;

    // XCD-chunked swizzle: XCD x (= bid%8) gets logical blocks [x*128, x*128+128)
    int raw = blockIdx.x;
    int lid = (raw & 7) * 128 + (raw >> 3);
    const int b = lid & 7;
    const int h = (lid >> 3) & 7;
    const int qt = lid >> 6;           // 0..15
    const int qbase = qt * 64 + wid * 16;
    const int bh = b * NH + h;

    // bpermute source-lane byte addresses for the P transform.
    // Target lane (qr,g) needs P[q=qr][k=8g+32c+j]; source k=16mt'+4g'+r' gives
    // g'=2*(g&1) (j<4) / +1 (j>=4), register W[2c+(g>>1)][j>>1].
    const int srcA = (qr + 32 * (g & 1)) << 2;
    const int srcB = srcA + 64;
    const bool hi = (g >> 1) != 0;

    // ---- Q fragments (B operand), scale*log2e folded ----
    const float* qp = q + ((size_t)(b * SEQ + qbase + qr) * DM + h * HD);
    short8 qf[2];
#pragma unroll
    for (int c = 0; c < 2; ++c) {
        float4 x0 = *(const float4*)(qp + g * 8 + 32 * c);
        float4 x1 = *(const float4*)(qp + g * 8 + 32 * c + 4);
        float xs[8] = {x0.x * QSCALE, x0.y * QSCALE, x0.z * QSCALE, x0.w * QSCALE,
                       x1.x * QSCALE, x1.y * QSCALE, x1.z * QSCALE, x1.w * QSCALE};
        qf[c] = pack8(xs);
    }

    f32x4 o[4];
#pragma unroll
    for (int nt = 0; nt < 4; ++nt) o[nt] = (f32x4){0.f, 0.f, 0.f, 0.f};
    float mrun = -INFINITY, lrun = 0.f;

    const size_t tb0 = (size_t)bh * 16 * 4096;

    u16x8 bn0, bn1;      // BM==0 prefetch regs
    float4 bnf[4];       // BM==1 prefetch regs

    // ---- prologue: stage tile 0, prefetch bias tile 0 ----
    {
        const short* gk = kws + tb0 + wid * 512 + lane * 8;
        const short* gv = vtws + tb0 + wid * 512 + lane * 8;
        gll16(gk,        &Ksh[0][wid * 512]);
        gll16(gk + 2048, &Ksh[0][2048 + wid * 512]);
        gll16(gv,        &Vsh[0][wid * 512]);
        gll16(gv + 2048, &Vsh[0][2048 + wid * 512]);
        if constexpr (BM == 0) {
            const unsigned short* bp =
                bias16 + ((size_t)((h * 16 + 0) * 1024 + qbase + qr) * 64 + g * 16);
            bn0 = *(const u16x8*)bp;
            bn1 = *(const u16x8*)(bp + 8);
        } else {
            const float* bp = bias32 + ((size_t)(h * SEQ + qbase + qr) * SEQ + g * 4);
#pragma unroll
            for (int mt = 0; mt < 4; ++mt) bnf[mt] = *(const float4*)(bp + 16 * mt);
        }
    }
    __syncthreads();

    int cur = 0;
    for (int kt = 0; kt < 16; ++kt) {
        // ---- snapshot this tile's bias from prefetch regs ----
        float bf[4][4];
        if constexpr (BM == 0) {
#pragma unroll
            for (int r = 0; r < 4; ++r) {
                bf[0][r] = h2f(bn0[r]);
                bf[1][r] = h2f(bn0[4 + r]);
                bf[2][r] = h2f(bn1[r]);
                bf[3][r] = h2f(bn1[4 + r]);
            }
        } else {
#pragma unroll
            for (int mt = 0; mt < 4; ++mt)
#pragma unroll
                for (int r = 0; r < 4; ++r) bf[mt][r] = ((const float*)&bnf[mt])[r];
        }

        // ---- stage next K/V tile ----
        if (kt < 15) {
            const size_t tb = tb0 + (size_t)(kt + 1) * 4096;
            const short* gk = kws + tb + wid * 512 + lane * 8;
            const short* gv = vtws + tb + wid * 512 + lane * 8;
            int nxt = cur ^ 1;
            gll16(gk,        &Ksh[nxt][wid * 512]);
            gll16(gk + 2048, &Ksh[nxt][2048 + wid * 512]);
            gll16(gv,        &Vsh[nxt][wid * 512]);
            gll16(gv + 2048, &Vsh[nxt][2048 + wid * 512]);
        }
        // ---- prefetch next tile's bias ----
        {
            int ktn = kt < 15 ? kt + 1 : 15;
            if constexpr (BM == 0) {
                const unsigned short* bp =
                    bias16 + ((size_t)((h * 16 + ktn) * 1024 + qbase + qr) * 64 + g * 16);
                bn0 = *(const u16x8*)bp;
                bn1 = *(const u16x8*)(bp + 8);
            } else {
                const float* bp =
                    bias32 + ((size_t)(h * SEQ + qbase + qr) * SEQ + ktn * 64 + g * 4);
#pragma unroll
                for (int mt = 0; mt < 4; ++mt) bnf[mt] = *(const float4*)(bp + 16 * mt);
            }
        }

        // ---- QK^T: S^T = mfma(K, Q); lane holds S[q=qr][k=16mt+4g+r] ----
        f32x4 acc[4];
#pragma unroll
        for (int mt = 0; mt < 4; ++mt) acc[mt] = (f32x4){0.f, 0.f, 0.f, 0.f};
        __builtin_amdgcn_s_setprio(1);
#pragma unroll
        for (int mt = 0; mt < 4; ++mt) {
#pragma unroll
            for (int c = 0; c < 2; ++c) {
                const short8 kf = *(const short8*)
                    &Ksh[cur][(qr + 16 * mt) * 64 + ((g + 4 * c) ^ (qr & 7)) * 8];
                acc[mt] = __builtin_amdgcn_mfma_f32_16x16x32_bf16(kf, qf[c], acc[mt], 0, 0, 0);
            }
        }
        __builtin_amdgcn_s_setprio(0);

        // ---- online softmax (exp2 domain), defer-max rescale ----
        float s[4][4];
        float tmax = -INFINITY;
#pragma unroll
        for (int mt = 0; mt < 4; ++mt)
#pragma unroll
            for (int r = 0; r < 4; ++r) {
                float val;
                if constexpr (BM == 0) val = acc[mt][r] + bf[mt][r];
                else                   val = fmaf(bf[mt][r], LOG2E, acc[mt][r]);
                s[mt][r] = val;
                tmax = fmaxf(tmax, val);
            }
        tmax = fmaxf(tmax, __shfl_xor(tmax, 16));
        tmax = fmaxf(tmax, __shfl_xor(tmax, 32));

        if (!__all(tmax <= mrun + RESCALE_THR)) {
            const float mnew = fmaxf(mrun, tmax);
            const float scs = fexp2(mrun - mnew);   // exp2(-inf)=0 first time
            float scr[4];
#pragma unroll
            for (int r = 0; r < 4; ++r) scr[r] = __shfl(scs, g * 4 + r);
#pragma unroll
            for (int nt = 0; nt < 4; ++nt)
#pragma unroll
                for (int r = 0; r < 4; ++r) o[nt][r] *= scr[r];
            lrun *= scs;
            mrun = mnew;
        }

        float ssum = 0.f;
        unsigned W[4][2];                  // packed bf16 P pairs: W[mt][w] = {k=16mt+4g+2w, +1}
#pragma unroll
        for (int mt = 0; mt < 4; ++mt) {
            float e0 = fexp2(s[mt][0] - mrun);
            float e1 = fexp2(s[mt][1] - mrun);
            float e2 = fexp2(s[mt][2] - mrun);
            float e3 = fexp2(s[mt][3] - mrun);
            ssum += (e0 + e1) + (e2 + e3);
            W[mt][0] = (unsigned)f2bf(e0) | ((unsigned)f2bf(e1) << 16);
            W[mt][1] = (unsigned)f2bf(e2) | ((unsigned)f2bf(e3) << 16);
        }
        ssum += __shfl_xor(ssum, 16);
        ssum += __shfl_xor(ssum, 32);
        lrun += ssum;

        // ---- PV: in-register P transform (bpermute) + mfma(P, V^T-frag) ----
#pragma unroll
        for (int c = 0; c < 2; ++c) {
            unsigned Ra[2][2], Rb[2][2];   // [mt-offset][w]
#pragma unroll
            for (int mo = 0; mo < 2; ++mo)
#pragma unroll
                for (int w = 0; w < 2; ++w) {
                    Ra[mo][w] = (unsigned)__builtin_amdgcn_ds_bpermute(srcA, (int)W[2 * c + mo][w]);
                    Rb[mo][w] = (unsigned)__builtin_amdgcn_ds_bpermute(srcB, (int)W[2 * c + mo][w]);
                }
            union { unsigned u[4]; short8 s8; } P_;
            P_.u[0] = hi ? Ra[1][0] : Ra[0][0];
            P_.u[1] = hi ? Ra[1][1] : Ra[0][1];
            P_.u[2] = hi ? Rb[1][0] : Rb[0][0];
            P_.u[3] = hi ? Rb[1][1] : Rb[0][1];
            const short8 pf = P_.s8;
            __builtin_amdgcn_s_setprio(1);
#pragma unroll
            for (int nt = 0; nt < 4; ++nt) {
                short8 vf = *(const short8*)
                    &Vsh[cur][(qr + 16 * nt) * 64 + ((g + 4 * c) ^ (qr & 7)) * 8];
                o[nt] = __builtin_amdgcn_mfma_f32_16x16x32_bf16(pf, vf, o[nt], 0, 0, 0);
            }
            __builtin_amdgcn_s_setprio(0);
        }

        __syncthreads();   // next tile staged + buffers protected
        cur ^= 1;
    }

    // ---- epilogue ----
    const float inv = 1.0f / lrun;
    float invr[4];
#pragma unroll
    for (int r = 0; r < 4; ++r) invr[r] = __shfl(inv, g * 4 + r);
    float* op = out + ((size_t)(b * SEQ + qbase) * DM + h * HD + qr);
#pragma unroll
    for (int nt = 0; nt < 4; ++nt)
#pragma unroll
        for (int r = 0; r < 4; ++r)
            op[(size_t)(g * 4 + r) * DM + nt * 16] = o[nt][r] * invr[r];
}

// ---------------- round-1 kernel kept as last-resort fallback ----------------
__global__ __launch_bounds__(256, 3)
void attn_fwd(const float* __restrict__ q, const float* __restrict__ k,
              const float* __restrict__ v, const float* __restrict__ bias,
              float* __restrict__ out)
{
    __shared__ short Klds[64][72];
    __shared__ short Vt[64][72];
    __shared__ short Pl[4][16][72];

    const int t = threadIdx.x;
    const int wid = t >> 6;
    const int lane = t & 63;
    const int qr = lane & 15;
    const int g = lane >> 4;

    int idx = blockIdx.x;
    const int b = idx & 7;  idx >>= 3;
    const int h = idx & 7;
    const int qtile = idx >> 3;
    const int qbase = qtile * 64 + wid * 16;

    const float* qp = q + ((b * SEQ + qbase + qr) * DM + h * HD);
    short8 qf[2];
#pragma unroll
    for (int c = 0; c < 2; ++c) {
        float4 x0 = *reinterpret_cast<const float4*>(qp + g * 8 + 32 * c);
        float4 x1 = *reinterpret_cast<const float4*>(qp + g * 8 + 32 * c + 4);
        float xs[8] = {x0.x * 0.125f, x0.y * 0.125f, x0.z * 0.125f, x0.w * 0.125f,
                       x1.x * 0.125f, x1.y * 0.125f, x1.z * 0.125f, x1.w * 0.125f};
        qf[c] = pack8(xs);
    }

    f32x4 o[4];
#pragma unroll
    for (int nt = 0; nt < 4; ++nt) o[nt] = (f32x4){0.f, 0.f, 0.f, 0.f};
    float mrun = -INFINITY, lrun = 0.f;

    const int jrow = t & 63;
    const int cc = t >> 6;

    for (int kt = 0; kt < 16; ++kt) {
        const int kbase = kt * 64;
        {
            const float4* kp4 = reinterpret_cast<const float4*>(
                k + ((b * SEQ + kbase + jrow) * DM + h * HD + cc * 16));
            float4 a0 = kp4[0], a1 = kp4[1], a2 = kp4[2], a3 = kp4[3];
            u16x4* dst = reinterpret_cast<u16x4*>(&Klds[jrow][cc * 16]);
            dst[0] = pack4(a0.x, a0.y, a0.z, a0.w);
            dst[1] = pack4(a1.x, a1.y, a1.z, a1.w);
            dst[2] = pack4(a2.x, a2.y, a2.z, a2.w);
            dst[3] = pack4(a3.x, a3.y, a3.z, a3.w);
        }
        {
            const float* vp = v + ((b * SEQ + kbase + cc * 16) * DM + h * HD + jrow);
            float vv[16];
#pragma unroll
            for (int jj = 0; jj < 16; ++jj) vv[jj] = vp[jj * DM];
            u16x4* dst = reinterpret_cast<u16x4*>(&Vt[jrow][cc * 16]);
            dst[0] = pack4(vv[0], vv[1], vv[2], vv[3]);
            dst[1] = pack4(vv[4], vv[5], vv[6], vv[7]);
            dst[2] = pack4(vv[8], vv[9], vv[10], vv[11]);
            dst[3] = pack4(vv[12], vv[13], vv[14], vv[15]);
        }
        __syncthreads();

        const float* bp = bias + ((h * SEQ + qbase + qr) * SEQ + kbase + g * 4);
        float4 bv0 = *reinterpret_cast<const float4*>(bp);
        float4 bv1 = *reinterpret_cast<const float4*>(bp + 16);
        float4 bv2 = *reinterpret_cast<const float4*>(bp + 32);
        float4 bv3 = *reinterpret_cast<const float4*>(bp + 48);

        f32x4 acc[4];
#pragma unroll
        for (int mt = 0; mt < 4; ++mt) {
            f32x4 a = (f32x4){0.f, 0.f, 0.f, 0.f};
#pragma unroll
            for (int c = 0; c < 2; ++c) {
                short8 kf = *reinterpret_cast<const short8*>(
                    &Klds[qr + 16 * mt][g * 8 + 32 * c]);
                a = __builtin_amdgcn_mfma_f32_16x16x32_bf16(kf, qf[c], a, 0, 0, 0);
            }
            acc[mt] = a;
        }
        acc[0][0] += bv0.x; acc[0][1] += bv0.y; acc[0][2] += bv0.z; acc[0][3] += bv0.w;
        acc[1][0] += bv1.x; acc[1][1] += bv1.y; acc[1][2] += bv1.z; acc[1][3] += bv1.w;
        acc[2][0] += bv2.x; acc[2][1] += bv2.y; acc[2][2] += bv2.z; acc[2][3] += bv2.w;
        acc[3][0] += bv3.x; acc[3][1] += bv3.y; acc[3][2] += bv3.z; acc[3][3] += bv3.w;

        float tmax = acc[0][0];
#pragma unroll
        for (int mt = 0; mt < 4; ++mt)
#pragma unroll
            for (int r = 0; r < 4; ++r) tmax = fmaxf(tmax, acc[mt][r]);
        tmax = fmaxf(tmax, __shfl_xor(tmax, 16));
        tmax = fmaxf(tmax, __shfl_xor(tmax, 32));
        const float mnew = fmaxf(mrun, tmax);

        float p[4][4];
        float ssum = 0.f;
#pragma unroll
        for (int mt = 0; mt < 4; ++mt)
#pragma unroll
            for (int r = 0; r < 4; ++r) {
                float e = __expf(acc[mt][r] - mnew);
                p[mt][r] = e;
                ssum += e;
            }
        ssum += __shfl_xor(ssum, 16);
        ssum += __shfl_xor(ssum, 32);
        const float scv = __expf(mrun - mnew);
        lrun = lrun * scv + ssum;
        mrun = mnew;

#pragma unroll
        for (int mt = 0; mt < 4; ++mt) {
            *reinterpret_cast<u16x4*>(&Pl[wid][qr][16 * mt + g * 4]) =
                pack4(p[mt][0], p[mt][1], p[mt][2], p[mt][3]);
        }

        float scr[4];
#pragma unroll
        for (int r = 0; r < 4; ++r) scr[r] = __shfl(scv, g * 4 + r);
#pragma unroll
        for (int nt = 0; nt < 4; ++nt)
#pragma unroll
            for (int r = 0; r < 4; ++r) o[nt][r] *= scr[r];

        asm volatile("s_waitcnt lgkmcnt(0)" ::: "memory");
        __builtin_amdgcn_sched_barrier(0);

        short8 pf0 = *reinterpret_cast<const short8*>(&Pl[wid][qr][g * 8]);
        short8 pf1 = *reinterpret_cast<const short8*>(&Pl[wid][qr][g * 8 + 32]);
#pragma unroll
        for (int nt = 0; nt < 4; ++nt) {
            short8 vf0 = *reinterpret_cast<const short8*>(&Vt[qr + 16 * nt][g * 8]);
            short8 vf1 = *reinterpret_cast<const short8*>(&Vt[qr + 16 * nt][g * 8 + 32]);
            o[nt] = __builtin_amdgcn_mfma_f32_16x16x32_bf16(pf0, vf0, o[nt], 0, 0, 0);
            o[nt] = __builtin_amdgcn_mfma_f32_16x16x32_bf16(pf1, vf1, o[nt], 0, 0, 0);
        }
        __syncthreads();
    }

    const float inv = 1.0f / lrun;
    float invr[4];
#pragma unroll
    for (int r = 0; r < 4; ++r) invr[r] = __shfl(inv, g * 4 + r);

    float* op = out + ((b * SEQ + qbase) * DM + h * HD + qr);
#pragma unroll
    for (int nt = 0; nt < 4; ++nt)
#pragma unroll
        for (int r = 0; r < 4; ++r)
            op[(g * 4 + r) * DM + nt * 16] = o[nt][r] * invr[r];
}

extern "C" void kernel_launch(void* const* d_in, const int* in_sizes, int n_in,
                              void* d_out, int out_size, void* d_ws, size_t ws_size,
                              hipStream_t stream) {
    const float* q    = (const float*)d_in[0];
    const float* k    = (const float*)d_in[1];
    const float* v    = (const float*)d_in[2];
    const float* bias = (const float*)d_in[3];
    float* out        = (float*)d_out;

    const size_t kv_elems  = (size_t)8 * NH * SEQ * HD;        // 4,194,304 shorts each
    const size_t kv_bytes  = 2 * kv_elems * sizeof(short);     // 16,777,216
    const size_t b16_bytes = (size_t)NH * SEQ * SEQ * 2;       // 16,777,216

    if (ws_size >= b16_bytes + kv_bytes) {
        unsigned short* b16 = (unsigned short*)d_ws;
        short* kws  = (short*)((char*)d_ws + b16_bytes);
        short* vtws = kws + kv_elems;
        prep_all<<<dim3(11264), dim3(256), 0, stream>>>(k, v, bias, kws, vtws, b16);
        attn_fwd3<0><<<dim3(1024), dim3(256), 0, stream>>>(q, nullptr, b16, kws, vtws, out);
    } else if (ws_size >= kv_bytes) {
        short* kws  = (short*)d_ws;
        short* vtws = kws + kv_elems;
        prep_all<<<dim3(11264), dim3(256), 0, stream>>>(k, v, bias, kws, vtws, nullptr);
        attn_fwd3<1><<<dim3(1024), dim3(256), 0, stream>>>(q, bias, nullptr, kws, vtws, out);
    } else {
        attn_fwd<<<dim3(1024), dim3(256), 0, stream>>>(q, k, v, bias, out);
    }
}